// Round 7
// baseline (86.281 us; speedup 1.0000x reference)
//
#include <hip/hip_runtime.h>
#include <math.h>

#define KG 128
#define CH 4
#define NCHUNK (KG / CH)

// Kernel 1: fold per-gaussian params once into d_ws.
//  P0[k] = (mux, muy, A', B')   A',B',C' = -0.5*log2e * sigma_inv coeffs
//  P1[k] = (C', alpha, col_r, col_g)
//  P2[k] = col_b
__global__ __launch_bounds__(128) void precompute_params(
    const float* __restrict__ mu,
    const float* __restrict__ alpha,
    const float* __restrict__ color,
    const float* __restrict__ scales,
    const float* __restrict__ thetas,
    float4* __restrict__ P0,
    float4* __restrict__ P1,
    float*  __restrict__ P2)
{
    const int k = threadIdx.x;
    if (k >= KG) return;
    const float mx = mu[2 * k];
    const float my = mu[2 * k + 1];
    const float al = fminf(fmaxf(alpha[k], 0.0f), 1.0f);
    const float cr = fminf(fmaxf(color[3 * k + 0], 0.0f), 255.0f);
    const float cg = fminf(fmaxf(color[3 * k + 1], 0.0f), 255.0f);
    const float cb = fminf(fmaxf(color[3 * k + 2], 0.0f), 255.0f);
    const float sx = fmaxf(scales[2 * k + 0], 0.1f);
    const float sy = fmaxf(scales[2 * k + 1], 0.1f);
    const float th = thetas[k];
    const float c = cosf(th);
    const float s = sinf(th);
    const float i0 = 1.0f / (sx * sx);
    const float i1 = 1.0f / (sy * sy);
    const float a  = c * c * i0 + s * s * i1;
    const float b  = c * s * (i0 - i1);
    const float cc = s * s * i0 + c * c * i1;
    const float f = -0.5f * 1.4426950408889634f;   // fold -0.5*log2(e) -> exp2
    P0[k] = make_float4(mx, my, a * f, 2.0f * b * f);
    P1[k] = make_float4(cc * f, al, cr, cg);
    P2[k] = cb;
}

// Kernel 2: ONE pixel per thread (1024 blocks -> 4 waves/SIMD, 2x R6's
// residency). Scalar f32, CH=4 chunked phases so exp2/rcp latencies overlap
// within a thread while 16 waves/CU cover the rest.
__global__ __launch_bounds__(256, 4) void splat_fwd(
    const float* __restrict__ pos,     // [N,2]
    const float4* __restrict__ P0,
    const float4* __restrict__ P1,
    const float*  __restrict__ P2,
    float* __restrict__ out,           // [N,4]
    int n)
{
    const int i = blockIdx.x * blockDim.x + threadIdx.x;
    if (i >= n) return;

    const float2 p = reinterpret_cast<const float2*>(pos)[i];
    const float px = p.x, py = p.y;

    float omp   = 1.0f;   // running transmittance (1 - pa)
    float pa    = 0.0f;   // running new_alpha (unclipped; <= 1 + ulp)
    float hprev = 0.0f;   // pa_{k-1} * r_{k-1}; unused at k=0 since num=0
    float rlast = 0.0f;
    float numr = 0.0f, numg = 0.0f, numb = 0.0f;

    for (int c = 0; c < NCHUNK; ++c) {
        const int base = c * CH;

        float4 q0[CH], q1[CH];
        float  q2[CH];
#pragma unroll
        for (int j = 0; j < CH; ++j) {
            q0[j] = P0[base + j];   // uniform index -> s_load (constant cache)
            q1[j] = P1[base + j];
            q2[j] = P2[base + j];
        }

        // A: weights — independent across j, exp2's pipeline
        float w[CH];
#pragma unroll
        for (int j = 0; j < CH; ++j) {
            const float dx = px - q0[j].x;
            const float dy = py - q0[j].y;
            const float u  = fmaf(q0[j].z, dx, q0[j].w * dy);
            const float e  = fmaf(dx, u, (q1[j].x * dy) * dy);
            w[j] = q1[j].y * __builtin_amdgcn_exp2f(e);
        }

        // B: short prefix chains (1 op/step each)
        float t1[CH], paA[CH];
#pragma unroll
        for (int j = 0; j < CH; ++j) {
            t1[j] = w[j] * omp;
            omp   = fmaf(-w[j], omp, omp);   // omp *= (1 - w)
            pa    = pa + t1[j];
            paA[j] = pa;
        }

        // C: independent reciprocals
        float r[CH];
#pragma unroll
        for (int j = 0; j < CH; ++j)
            r[j] = __builtin_amdgcn_rcpf(paA[j] + 1e-8f);

        // D: 3 parallel per-channel numerator fma chains
#pragma unroll
        for (int j = 0; j < CH; ++j) {
            numr = fmaf(numr, hprev, q1[j].z * t1[j]);
            numg = fmaf(numg, hprev, q1[j].w * t1[j]);
            numb = fmaf(numb, hprev, q2[j]   * t1[j]);
            hprev = paA[j] * r[j];
        }
        rlast = r[CH - 1];
    }

    float4 o;
    o.x = fminf(fmaxf(numr * rlast, 0.0f), 255.0f);
    o.y = fminf(fmaxf(numg * rlast, 0.0f), 255.0f);
    o.z = fminf(fmaxf(numb * rlast, 0.0f), 255.0f);
    o.w = fminf(pa, 1.0f) * 255.0f;
    reinterpret_cast<float4*>(out)[i] = o;
}

extern "C" void kernel_launch(void* const* d_in, const int* in_sizes, int n_in,
                              void* d_out, int out_size, void* d_ws, size_t ws_size,
                              hipStream_t stream) {
    const float* pos    = (const float*)d_in[0];
    const float* mu     = (const float*)d_in[1];
    const float* alpha  = (const float*)d_in[2];
    const float* color  = (const float*)d_in[3];
    const float* scales = (const float*)d_in[4];
    const float* thetas = (const float*)d_in[5];
    float* out = (float*)d_out;

    // Param buffer layout in d_ws: P0[K] | P1[K] | P2[K]
    float4* P0 = (float4*)d_ws;
    float4* P1 = P0 + KG;
    float*  P2 = (float*)(P1 + KG);

    const int n = in_sizes[0] / 2;       // N pixels
    const int block = 256;
    const int grid = (n + block - 1) / block;

    hipLaunchKernelGGL(precompute_params, dim3(1), dim3(128), 0, stream,
                       mu, alpha, color, scales, thetas, P0, P1, P2);
    hipLaunchKernelGGL(splat_fwd, dim3(grid), dim3(block), 0, stream,
                       pos, P0, P1, P2, out, n);
}

// Round 8
// 81.152 us; speedup vs baseline: 1.0632x; 1.0632x over previous
//
#include <hip/hip_runtime.h>
#include <math.h>

#define KG 128
#define CH 4
#define NCHUNK (KG / CH)

typedef float f32x2 __attribute__((ext_vector_type(2)));

// Single-kernel 2D gaussian splat, eps-exact numerator recurrence.
//  - params folded once per block into LDS (broadcast reads)
//  - log2(alpha) folded into the exponent: w = exp2(e + lal)
//  - 2 pixels/thread (f32x2 -> packed math), CH=4 chunked phases for ILP
__global__ __launch_bounds__(256, 2) void splat_fwd(
    const float* __restrict__ pos,     // [N,2]
    const float* __restrict__ mu,      // [K,2]
    const float* __restrict__ alpha,   // [K]
    const float* __restrict__ color,   // [K,3]
    const float* __restrict__ scales,  // [K,2]
    const float* __restrict__ thetas,  // [K]
    float* __restrict__ out,           // [N,4]
    int nPairs)
{
    __shared__ float4 sP0[KG];  // mux, muy, A', B'   (A',B',C' = -0.5*log2e * sigma_inv)
    __shared__ float4 sP1[KG];  // C', lal, col_r, col_g
    __shared__ float  sP2[KG];  // col_b

    const int tid = threadIdx.x;
    if (tid < KG) {
        const int k = tid;
        const float mx = mu[2 * k];
        const float my = mu[2 * k + 1];
        const float al = fminf(fmaxf(alpha[k], 0.0f), 1.0f);
        const float cr = fminf(fmaxf(color[3 * k + 0], 0.0f), 255.0f);
        const float cg = fminf(fmaxf(color[3 * k + 1], 0.0f), 255.0f);
        const float cb = fminf(fmaxf(color[3 * k + 2], 0.0f), 255.0f);
        const float sx = fmaxf(scales[2 * k + 0], 0.1f);
        const float sy = fmaxf(scales[2 * k + 1], 0.1f);
        const float th = thetas[k];
        const float c = cosf(th);
        const float s = sinf(th);
        const float i0 = 1.0f / (sx * sx);
        const float i1 = 1.0f / (sy * sy);
        const float a  = c * c * i0 + s * s * i1;
        const float b  = c * s * (i0 - i1);
        const float cc = s * s * i0 + c * c * i1;
        const float f = -0.5f * 1.4426950408889634f;   // -0.5*log2(e)
        const float lal = __log2f(al);                 // -inf at al==0 is fine
        sP0[k] = make_float4(mx, my, a * f, 2.0f * b * f);
        sP1[k] = make_float4(cc * f, lal, cr, cg);
        sP2[k] = cb;
    }
    __syncthreads();

    const int t = blockIdx.x * blockDim.x + tid;   // pixel-pair index
    if (t >= nPairs) return;

    const float4 pp = reinterpret_cast<const float4*>(pos)[t]; // x0,y0,x1,y1
    const f32x2 px = { pp.x, pp.z };
    const f32x2 py = { pp.y, pp.w };

    f32x2 omp   = { 1.0f, 1.0f };   // running transmittance (1 - pa)
    f32x2 pa    = { 0.0f, 0.0f };   // running new_alpha (unclipped; <= 1+ulp)
    f32x2 hprev = { 0.0f, 0.0f };   // pa_{k-1}*r_{k-1}; unused at k=0 (num=0)
    f32x2 rlast = { 0.0f, 0.0f };
    f32x2 numr  = { 0.0f, 0.0f };
    f32x2 numg  = { 0.0f, 0.0f };
    f32x2 numb  = { 0.0f, 0.0f };

    for (int c = 0; c < NCHUNK; ++c) {
        const int base = c * CH;

        float4 q0[CH], q1[CH];
        float  q2[CH];
#pragma unroll
        for (int j = 0; j < CH; ++j) {
            q0[j] = sP0[base + j];
            q1[j] = sP1[base + j];
            q2[j] = sP2[base + j];
        }

        // A: weights — independent across j; w = exp2(e + lal)
        f32x2 w[CH];
#pragma unroll
        for (int j = 0; j < CH; ++j) {
            const f32x2 dx = px - q0[j].x;
            const f32x2 dy = py - q0[j].y;
            const f32x2 u  = q0[j].z * dx + q0[j].w * dy;         // A*dx + B*dy
            const f32x2 v  = (q1[j].x * dy) * dy + q1[j].y;       // C*dy^2 + lal
            const f32x2 e  = dx * u + v;
            w[j].x = __builtin_amdgcn_exp2f(e.x);
            w[j].y = __builtin_amdgcn_exp2f(e.y);
        }

        // B: short prefix chains
        f32x2 t1[CH], paA[CH];
#pragma unroll
        for (int j = 0; j < CH; ++j) {
            t1[j] = w[j] * omp;
            omp   = omp - w[j] * omp;      // omp *= (1 - w)
            pa    = pa + t1[j];
            paA[j] = pa;
        }

        // C: independent reciprocals
        f32x2 r[CH];
#pragma unroll
        for (int j = 0; j < CH; ++j) {
            const f32x2 nae = paA[j] + 1e-8f;
            r[j].x = __builtin_amdgcn_rcpf(nae.x);
            r[j].y = __builtin_amdgcn_rcpf(nae.y);
        }

        // D: 3 parallel per-channel numerator fma chains
#pragma unroll
        for (int j = 0; j < CH; ++j) {
            numr = numr * hprev + q1[j].z * t1[j];
            numg = numg * hprev + q1[j].w * t1[j];
            numb = numb * hprev + q2[j]   * t1[j];
            hprev = paA[j] * r[j];
        }
        rlast = r[CH - 1];
    }

    const f32x2 pcr = numr * rlast;
    const f32x2 pcg = numg * rlast;
    const f32x2 pcb = numb * rlast;

    float4 o0, o1;
    o0.x = fminf(fmaxf(pcr.x, 0.0f), 255.0f);
    o0.y = fminf(fmaxf(pcg.x, 0.0f), 255.0f);
    o0.z = fminf(fmaxf(pcb.x, 0.0f), 255.0f);
    o0.w = fminf(pa.x, 1.0f) * 255.0f;
    o1.x = fminf(fmaxf(pcr.y, 0.0f), 255.0f);
    o1.y = fminf(fmaxf(pcg.y, 0.0f), 255.0f);
    o1.z = fminf(fmaxf(pcb.y, 0.0f), 255.0f);
    o1.w = fminf(pa.y, 1.0f) * 255.0f;

    float4* o = reinterpret_cast<float4*>(out);
    o[2 * t]     = o0;
    o[2 * t + 1] = o1;
}

extern "C" void kernel_launch(void* const* d_in, const int* in_sizes, int n_in,
                              void* d_out, int out_size, void* d_ws, size_t ws_size,
                              hipStream_t stream) {
    const float* pos    = (const float*)d_in[0];
    const float* mu     = (const float*)d_in[1];
    const float* alpha  = (const float*)d_in[2];
    const float* color  = (const float*)d_in[3];
    const float* scales = (const float*)d_in[4];
    const float* thetas = (const float*)d_in[5];
    float* out = (float*)d_out;

    const int n = in_sizes[0] / 2;       // N pixels
    const int nPairs = n / 2;            // N even (512*512)
    const int block = 256;
    const int grid = (nPairs + block - 1) / block;

    hipLaunchKernelGGL(splat_fwd, dim3(grid), dim3(block), 0, stream,
                       pos, mu, alpha, color, scales, thetas, out, nPairs);
}